// Round 1
// 73.349 us; speedup vs baseline: 1.0409x; 1.0409x over previous
//
#include <hip/hip_runtime.h>
#include <cstdint>

// Problem constants (from reference)
#define B 64
#define P 5000
#define G 300
#define C 20
#define SCALE_F 512.0f
#define IOU_TH 0.5f
#define NSPLIT 8                              // pred chunks per image (was 4; 2 blocks/CU now)
#define PCHUNK ((P + NSPLIT - 1) / NSPLIT)    // 625
#define NTA 512
#define SPT ((PCHUNK + NTA - 1) / NTA)        // 2 slots per thread
#define SENT 0x7FFFFFFF

// Match numpy float32 semantics exactly: no FMA contraction (hipcc defaults
// to contract=fast). Division stays IEEE (no fast-math).
#pragma clang fp contract(off)

// ---------------------------------------------------------------------------
// Kernel A: grid (NSPLIT, B) = 512 blocks (2 blocks/CU -> 16 waves/CU, was
// 25% occupancy at 1 block/CU), 512 threads. Per block: stable class-sort of
// its image's targets in LDS (stability preserves the jnp.argmax
// first-occurrence tie-break), unstable class-sort of its 625-pred chunk
// (wave lanes then process same-class preds -> uniform bucket bounds +
// broadcast LDS reads), match, claim via LDS atomicMin into a block-private
// firstp, then dump it to blockfp[b][s][*].
// NEW this round: match is now the sole dense writer of out_stats. corr is
// written as 0 for every pred (score/cls come straight from registers); the
// resolve kernel only flips the <=G winners per image to 1.0. gbest is gone.
// out_tcls is written here too (s==0 blocks already load the labels).
// Key identity: the reference argmax does not depend on `detected`, so the
// sequential scan == "first eligible claimant (lowest p) per target wins",
// and lf[t] != SENT => pred lf[t] is the unique winner of target t.
// ---------------------------------------------------------------------------
__global__ __launch_bounds__(NTA, 4) void match_kernel(
    const float* __restrict__ preds,      // [B,P,6]
    const float* __restrict__ labels,     // [B,G,5]
    int* __restrict__ blockfp,            // [B,NSPLIT,G]
    float* __restrict__ out_stats,        // [B,P,3]
    float* __restrict__ out_tcls)         // [B,G]
{
    const int s = blockIdx.x;
    const int b = blockIdx.y;
    const int tid = threadIdx.x;

    __shared__ float4 sb[G];              // class-sorted scaled target boxes
    __shared__ float  sa[G];              // areas
    __shared__ short  ssi[G];             // sorted pos -> original target idx
    __shared__ short  cls_s[G];           // target class (original order)
    __shared__ int    so[C + 1];          // target bucket offsets
    __shared__ int    cnt[C];
    __shared__ int    pcnt[C];            // pred histogram -> running offset
    __shared__ int    firstp[G];          // chunk-local lowest claimant
    __shared__ unsigned short psorted[PCHUNK]; // slot -> global pred idx

    const float* lab = labels + (size_t)b * G * 5;
    const float* prd = preds + (size_t)b * P * 6;
    const int pbase = s * PCHUNK;

    // ---- init + target classes (+ out_tcls from the value already loaded) ----
    if (tid < C) { cnt[tid] = 0; pcnt[tid] = 0; }
    for (int t = tid; t < G; t += NTA) {
        float cf = lab[t * 5 + 4];
        cls_s[t] = (short)(int)cf;
        firstp[t] = SENT;
        if (s == 0) out_tcls[(size_t)b * G + t] = cf;
    }
    __syncthreads();

    // ---- histograms ----
    for (int t = tid; t < G; t += NTA) atomicAdd(&cnt[cls_s[t]], 1);
    #pragma unroll
    for (int k = 0; k < SPT; ++k) {
        int p = pbase + k * NTA + tid;
        if (p < pbase + PCHUNK)
            atomicAdd(&pcnt[(int)prd[p * 6 + 5]], 1);
    }
    __syncthreads();

    // ---- exclusive scans (two serial threads in different waves) ----
    if (tid == 0) {
        int a = 0;
        for (int c = 0; c < C; ++c) { so[c] = a; a += cnt[c]; }
        so[C] = a;
    }
    if (tid == 64) {
        int a = 0;
        for (int c = 0; c < C; ++c) { int v = pcnt[c]; pcnt[c] = a; a += v; }
    }
    __syncthreads();

    // ---- stable target scatter ----
    for (int t = tid; t < G; t += NTA) {
        short c = cls_s[t];
        int rank = 0;
        for (int u = 0; u < t; ++u) rank += (cls_s[u] == c) ? 1 : 0;
        int pos = so[c] + rank;
        float x1 = lab[t * 5 + 0] * SCALE_F;   // *512 exact (pow2)
        float y1 = lab[t * 5 + 1] * SCALE_F;
        float x2 = lab[t * 5 + 2] * SCALE_F;
        float y2 = lab[t * 5 + 3] * SCALE_F;
        sb[pos] = make_float4(x1, y1, x2, y2);
        sa[pos] = (x2 - x1) * (y2 - y1);
        ssi[pos] = (short)t;
    }
    // ---- unstable pred scatter (order within bucket irrelevant) ----
    #pragma unroll
    for (int k = 0; k < SPT; ++k) {
        int p = pbase + k * NTA + tid;
        if (p < pbase + PCHUNK) {
            int c = (int)prd[p * 6 + 5];      // L2-hot re-read
            int pos = atomicAdd(&pcnt[c], 1);
            psorted[pos] = (unsigned short)p;
        }
    }
    __syncthreads();

    // ---- match (slot-ordered: lanes mostly same class) ----
    #pragma unroll
    for (int k = 0; k < SPT; ++k) {
        int slot = k * NTA + tid;
        if (slot >= PCHUNK) continue;
        int p = psorted[slot];
        const float* pr = prd + p * 6;
        float px1 = pr[0] * SCALE_F;
        float py1 = pr[1] * SCALE_F;
        float px2 = pr[2] * SCALE_F;
        float py2 = pr[3] * SCALE_F;
        float score = pr[4];
        float clsf = pr[5];
        int c = (int)clsf;
        float parea = (px2 - px1) * (py2 - py1);

        int lo = so[c], hi = so[c + 1];
        float best = -1.0f;
        int bi = -1;
        // bucket preserves original order; strict > keeps FIRST max occurrence
        for (int j = lo; j < hi; ++j) {
            float4 tb = sb[j];                 // wave-uniform j -> broadcast
            float lx = fmaxf(px1, tb.x);
            float ly = fmaxf(py1, tb.y);
            float rx = fminf(px2, tb.z);
            float ry = fminf(py2, tb.w);
            float w = fmaxf(rx - lx, 0.0f);
            float h = fmaxf(ry - ly, 0.0f);
            float inter = w * h;
            float uni = (parea + sa[j]) - inter;   // reference assoc order
            float iou = inter / uni;               // IEEE div
            if (iou > best) { best = iou; bi = ssi[j]; }
        }

        bool eligible = (score > 0.0f) && (hi > lo) && (best > IOU_TH);
        if (eligible) atomicMin(&firstp[bi], p);

        // dense stats store: corr defaults to 0; resolve flips winners to 1
        size_t ip3 = ((size_t)b * P + p) * 3;
        out_stats[ip3 + 0] = 0.0f;
        out_stats[ip3 + 1] = score;
        out_stats[ip3 + 2] = clsf;
    }
    __syncthreads();

    // ---- dump chunk-local claims (coalesced) ----
    for (int t = tid; t < G; t += NTA)
        blockfp[((size_t)b * NSPLIT + s) * G + t] = firstp[t];
}

// ---------------------------------------------------------------------------
// Kernel B: tiny sparse resolve. One block per image; thread t min-reduces
// the NSPLIT chunk-local claims for target t; if a winner exists, that pred
// gets corr=1.0 (a single 4B store; <=300 stores per image). lf[t]=p implies
// p claimed t (p claims only its own argmax), so no index array is needed.
// Kernel boundary guarantees visibility/ordering of kernel A's stores.
// ---------------------------------------------------------------------------
__global__ __launch_bounds__(320) void resolve_kernel(
    const int* __restrict__ blockfp,      // [B,NSPLIT,G]
    float* __restrict__ out_stats)        // [B,P,3]
{
    const int b = blockIdx.x;
    const int t = threadIdx.x;
    if (t >= G) return;

    const int* fp = blockfp + (size_t)b * NSPLIT * G + t;
    int m = fp[0];
    #pragma unroll
    for (int s = 1; s < NSPLIT; ++s) m = min(m, fp[s * G]);

    if (m != SENT)
        out_stats[((size_t)b * P + m) * 3] = 1.0f;
}

extern "C" void kernel_launch(void* const* d_in, const int* in_sizes, int n_in,
                              void* d_out, int out_size, void* d_ws, size_t ws_size,
                              hipStream_t stream) {
    const float* output = (const float*)d_in[0];   // [B,P,6]
    const float* labels = (const float*)d_in[1];   // [B,G,5]

    float* out_stats = (float*)d_out;                       // [B,P,3]
    float* out_tcls  = (float*)d_out + (size_t)B * P * 3;   // [B,G]

    // workspace layout (no init required — kernel A writes every slot)
    int* blockfp = (int*)d_ws;                              // B*NSPLIT*G

    dim3 grid(NSPLIT, B);
    match_kernel<<<grid, NTA, 0, stream>>>(output, labels, blockfp,
                                           out_stats, out_tcls);
    resolve_kernel<<<dim3(B), 320, 0, stream>>>(blockfp, out_stats);
}